// Round 1
// baseline (318.822 us; speedup 1.0000x reference)
//
#include <hip/hip_runtime.h>
#include <math.h>

#define Bsz 4
#define Tn 2048
#define Cn 1024
#define Hn 64

// ---------------------------------------------------------------------------
// Kernel A: QKV projection.  grid (128, 3), block 256.
// Each block: 64 rows (of B*T=8192) x 64 outputs for one of {k,q,v}.
// Thread: 2 rows x 8 outputs (interleaved by 8) -> 10 LDS reads per 16 FMA.
// LDS strides padded to 68 (16B-aligned float4 stores, <=2-way bank conflicts).
// ---------------------------------------------------------------------------
__global__ __launch_bounds__(256) void qkv_proj(
    const float* __restrict__ x,
    const float* __restrict__ Wk, const float* __restrict__ Wq,
    const float* __restrict__ Wv,
    float* __restrict__ ko, float* __restrict__ qo, float* __restrict__ vo)
{
    __shared__ float xs[64 * 68];
    __shared__ float wsm[64 * 68];

    const int tid = threadIdx.x;
    const int mat = blockIdx.y;
    const float* __restrict__ W = (mat == 0) ? Wk : (mat == 1) ? Wq : Wv;
    float* __restrict__ out = (mat == 0) ? ko : (mat == 1) ? qo : vo;

    const int row0 = blockIdx.x * 64;
    const int lr  = tid >> 3;   // 0..31 -> rows lr and lr+32
    const int sub = tid & 7;    // outputs o = sub + 8*j

    float acc0[8], acc1[8];
#pragma unroll
    for (int j = 0; j < 8; ++j) { acc0[j] = 0.f; acc1[j] = 0.f; }

    for (int c0 = 0; c0 < Cn; c0 += 64) {
        __syncthreads();
        // stage x tile [64][64] and W tile [64][64] as float4
#pragma unroll
        for (int i = 0; i < 4; ++i) {
            int fidx = tid + 256 * i;        // 0..1023 float4 slots
            int r  = fidx >> 4;              // 16 float4 per row
            int cc = (fidx & 15) << 2;
            float4 xv = *reinterpret_cast<const float4*>(
                &x[(size_t)(row0 + r) * Cn + c0 + cc]);
            *reinterpret_cast<float4*>(&xs[r * 68 + cc]) = xv;
            float4 wv = *reinterpret_cast<const float4*>(
                &W[(size_t)r * Cn + c0 + cc]);
            *reinterpret_cast<float4*>(&wsm[r * 68 + cc]) = wv;
        }
        __syncthreads();
#pragma unroll 4
        for (int c = 0; c < 64; ++c) {
            float xv0 = xs[lr * 68 + c];
            float xv1 = xs[(lr + 32) * 68 + c];
#pragma unroll
            for (int j = 0; j < 8; ++j) {
                float wv = wsm[(sub + (j << 3)) * 68 + c];
                acc0[j] += xv0 * wv;
                acc1[j] += xv1 * wv;
            }
        }
    }
#pragma unroll
    for (int j = 0; j < 8; ++j) {
        out[(size_t)(row0 + lr) * Hn + sub + (j << 3)]      = acc0[j];
        out[(size_t)(row0 + lr + 32) * Hn + sub + (j << 3)] = acc1[j];
    }
}

// ---------------------------------------------------------------------------
// Kernel B: causal flash attention.  grid 256 (= B * T/32), block 256.
// Block: 32 query rows; key tiles of 64; online softmax.
// Thread (lr=tid>>3, sub=tid&7): 8 interleaved keys j=sub+8*jj for scores,
// 8 contiguous output dims d=sub*8.. for PV.  LDS stride 65 -> conflict-free.
// ---------------------------------------------------------------------------
__global__ __launch_bounds__(256) void attn(
    const float* __restrict__ qb, const float* __restrict__ kb,
    const float* __restrict__ vb, float* __restrict__ out)
{
    __shared__ float qs[32 * 65];
    __shared__ float ks[64 * 65];
    __shared__ float vs[64 * 65];
    __shared__ float ps[32 * 65];

    const int tid = threadIdx.x;
    const int b  = blockIdx.x >> 6;
    const int qt = blockIdx.x & 63;
    const int t0 = qt * 32;

    // stage Q tile [32][64], pre-scaled by C^-0.5 = 1/32
    const float* __restrict__ qbase = qb + ((size_t)b * Tn + t0) * Hn;
    for (int i = tid; i < 512; i += 256) {       // 512 float4
        int r = i >> 4; int cc = (i & 15) << 2;
        float4 v = *reinterpret_cast<const float4*>(&qbase[r * Hn + cc]);
        const float s = 0.03125f;
        qs[r * 65 + cc]     = v.x * s;
        qs[r * 65 + cc + 1] = v.y * s;
        qs[r * 65 + cc + 2] = v.z * s;
        qs[r * 65 + cc + 3] = v.w * s;
    }

    const int lr  = tid >> 3;   // query row 0..31
    const int sub = tid & 7;

    float m = -INFINITY, l = 0.f;
    float O[8];
#pragma unroll
    for (int d = 0; d < 8; ++d) O[d] = 0.f;

    const int nkt = (t0 + 31) / 64 + 1;
    for (int kt = 0; kt < nkt; ++kt) {
        __syncthreads();   // previous PV done with vs/ps
        const float* __restrict__ kbase = kb + ((size_t)b * Tn + kt * 64) * Hn;
        const float* __restrict__ vbase = vb + ((size_t)b * Tn + kt * 64) * Hn;
#pragma unroll
        for (int i = 0; i < 4; ++i) {
            int fidx = tid + 256 * i;            // 1024 float4 slots
            int r = fidx >> 4; int cc = (fidx & 15) << 2;
            float4 kv = *reinterpret_cast<const float4*>(&kbase[r * Hn + cc]);
            ks[r * 65 + cc] = kv.x; ks[r * 65 + cc + 1] = kv.y;
            ks[r * 65 + cc + 2] = kv.z; ks[r * 65 + cc + 3] = kv.w;
            float4 vv = *reinterpret_cast<const float4*>(&vbase[r * Hn + cc]);
            vs[r * 65 + cc] = vv.x; vs[r * 65 + cc + 1] = vv.y;
            vs[r * 65 + cc + 2] = vv.z; vs[r * 65 + cc + 3] = vv.w;
        }
        __syncthreads();

        // scores: 8 keys per thread, j = sub + 8*jj (conflict-free reads)
        float s[8];
#pragma unroll
        for (int jj = 0; jj < 8; ++jj) s[jj] = 0.f;
#pragma unroll 4
        for (int c = 0; c < 64; ++c) {
            float qv = qs[lr * 65 + c];
#pragma unroll
            for (int jj = 0; jj < 8; ++jj)
                s[jj] += qv * ks[(sub + (jj << 3)) * 65 + c];
        }
        // causal mask
        const int tq = t0 + lr;
#pragma unroll
        for (int jj = 0; jj < 8; ++jj) {
            int kg = kt * 64 + sub + (jj << 3);
            if (kg > tq) s[jj] = -INFINITY;
        }
        // online softmax (8-lane group reduction)
        float tm = s[0];
#pragma unroll
        for (int jj = 1; jj < 8; ++jj) tm = fmaxf(tm, s[jj]);
        for (int off = 1; off < 8; off <<= 1)
            tm = fmaxf(tm, __shfl_xor(tm, off, 64));
        float nm = fmaxf(m, tm);
        float alpha = __expf(m - nm);   // m=-inf on tile 0 -> alpha=0
        float p[8], psum = 0.f;
#pragma unroll
        for (int jj = 0; jj < 8; ++jj) {
            p[jj] = __expf(s[jj] - nm);  // masked -> exp(-inf) = 0
            psum += p[jj];
        }
        for (int off = 1; off < 8; off <<= 1)
            psum += __shfl_xor(psum, off, 64);
        l = l * alpha + psum;
        m = nm;
#pragma unroll
        for (int d = 0; d < 8; ++d) O[d] *= alpha;
        // share P across the row's 8 lanes via LDS
#pragma unroll
        for (int jj = 0; jj < 8; ++jj)
            ps[lr * 65 + sub + (jj << 3)] = p[jj];
        __syncthreads();
        // PV: O[d] += P[row][j] * V[j][d], d = sub*8..sub*8+7
#pragma unroll 4
        for (int j = 0; j < 64; ++j) {
            float pv = ps[lr * 65 + j];
#pragma unroll
            for (int d = 0; d < 8; ++d)
                O[d] += pv * vs[j * 65 + (sub << 3) + d];
        }
    }

    const float inv = 1.f / l;
    float* obase = out + ((size_t)b * Tn + t0 + lr) * Hn + (sub << 3);
    float4 o0 = make_float4(O[0] * inv, O[1] * inv, O[2] * inv, O[3] * inv);
    float4 o1 = make_float4(O[4] * inv, O[5] * inv, O[6] * inv, O[7] * inv);
    *reinterpret_cast<float4*>(obase)     = o0;
    *reinterpret_cast<float4*>(obase + 4) = o1;
}

extern "C" void kernel_launch(void* const* d_in, const int* in_sizes, int n_in,
                              void* d_out, int out_size, void* d_ws, size_t ws_size,
                              hipStream_t stream) {
    const float* x  = (const float*)d_in[0];
    const float* Wk = (const float*)d_in[1];
    const float* Wq = (const float*)d_in[2];
    const float* Wv = (const float*)d_in[3];
    float* out = (float*)d_out;

    const size_t rows = (size_t)Bsz * Tn;           // 8192
    float* qbuf = (float*)d_ws;                     // [8192][64]
    float* kbuf = qbuf + rows * Hn;
    float* vbuf = kbuf + rows * Hn;

    dim3 gridA(128, 3);
    qkv_proj<<<gridA, 256, 0, stream>>>(x, Wk, Wq, Wv, kbuf, qbuf, vbuf);

    dim3 gridB(Bsz * (Tn / 32));                    // 256 blocks
    attn<<<gridB, 256, 0, stream>>>(qbuf, kbuf, vbuf, out);
}

// Round 2
// 96.252 us; speedup vs baseline: 3.3124x; 3.3124x over previous
//
#include <hip/hip_runtime.h>
#include <math.h>

#define Tn 2048
#define Cn 1024
#define Hn 64

using u16 = unsigned short;
typedef float f32x4 __attribute__((ext_vector_type(4)));
typedef __bf16 bf16x8 __attribute__((ext_vector_type(8)));
typedef u16 u16x8 __attribute__((ext_vector_type(8)));
typedef u16 u16x4 __attribute__((ext_vector_type(4)));

__device__ __forceinline__ u16 f2bf(float f) {
    return __builtin_bit_cast(u16, static_cast<__bf16>(f));
}

// ---------------------------------------------------------------------------
// QKV projection, bf16 MFMA.  grid 128, block 512 (8 waves).
// Block tile: 64 rows x 192 outs (k|q|v stacked), K-step 64.
// Wave (w&3)=row-group of 16, (w>>2)=96-col half.  12 MFMA/wave/step.
// LDS tiles stride 72 bf16 (144B rows -> <=2-way bank conflicts).
// Outputs bf16; q pre-scaled by C^-0.5 = 1/32.
// ---------------------------------------------------------------------------
__global__ __launch_bounds__(512) void qkv_proj(
    const float* __restrict__ x,
    const float* __restrict__ Wk, const float* __restrict__ Wq,
    const float* __restrict__ Wv,
    u16* __restrict__ kb, u16* __restrict__ qb, u16* __restrict__ vb)
{
    __shared__ u16 xs[64 * 72];
    __shared__ u16 wsm[192 * 72];

    const int tid  = threadIdx.x;
    const int lane = tid & 63;
    const int w    = tid >> 6;
    const int wr   = (w & 3) * 16;   // row base within 64
    const int wc   = (w >> 2) * 96;  // col base within 192
    const int l15  = lane & 15;
    const int lg   = lane >> 4;
    const int row0 = blockIdx.x * 64;

    f32x4 acc[6];
#pragma unroll
    for (int nt = 0; nt < 6; ++nt)
#pragma unroll
        for (int r = 0; r < 4; ++r) acc[nt][r] = 0.f;

    for (int c0 = 0; c0 < Cn; c0 += 64) {
        __syncthreads();
        // stage x [64][64] f32 -> bf16
#pragma unroll
        for (int i = 0; i < 2; ++i) {
            int cx = tid + 512 * i;                 // 0..1023 float4 chunks
            int r = cx >> 4, c4 = (cx & 15) << 2;
            float4 v = *reinterpret_cast<const float4*>(
                &x[(size_t)(row0 + r) * Cn + c0 + c4]);
            u16x4 h;
            h[0] = f2bf(v.x); h[1] = f2bf(v.y);
            h[2] = f2bf(v.z); h[3] = f2bf(v.w);
            *reinterpret_cast<u16x4*>(&xs[r * 72 + c4]) = h;
        }
        // stage W rows: 0-63 Wk, 64-127 Wq, 128-191 Wv
#pragma unroll
        for (int i = 0; i < 6; ++i) {
            int cw = tid + 512 * i;                 // 0..3071
            int r = cw >> 4, c4 = (cw & 15) << 2;
            const float* __restrict__ Wm = (r < 64) ? Wk : (r < 128) ? Wq : Wv;
            float4 v = *reinterpret_cast<const float4*>(
                &Wm[(size_t)(r & 63) * Cn + c0 + c4]);
            u16x4 h;
            h[0] = f2bf(v.x); h[1] = f2bf(v.y);
            h[2] = f2bf(v.z); h[3] = f2bf(v.w);
            *reinterpret_cast<u16x4*>(&wsm[r * 72 + c4]) = h;
        }
        __syncthreads();
#pragma unroll
        for (int kc = 0; kc < 2; ++kc) {
            bf16x8 a = *reinterpret_cast<const bf16x8*>(
                &xs[(wr + l15) * 72 + kc * 32 + (lg << 3)]);
#pragma unroll
            for (int nt = 0; nt < 6; ++nt) {
                bf16x8 bfr = *reinterpret_cast<const bf16x8*>(
                    &wsm[(wc + nt * 16 + l15) * 72 + kc * 32 + (lg << 3)]);
                acc[nt] = __builtin_amdgcn_mfma_f32_16x16x32_bf16(a, bfr, acc[nt], 0, 0, 0);
            }
        }
    }
    // epilogue: D row=(lg<<2)+reg, col=l15 (verified layout)
#pragma unroll
    for (int nt = 0; nt < 6; ++nt) {
        int n0  = wc + nt * 16;
        int mat = n0 >> 6;
        u16* __restrict__ ob = (mat == 0) ? kb : (mat == 1) ? qb : vb;
        float scale = (mat == 1) ? 0.03125f : 1.0f;
        int h = (n0 & 63) + l15;
#pragma unroll
        for (int reg = 0; reg < 4; ++reg) {
            int grow = row0 + wr + (lg << 2) + reg;
            ob[(size_t)grow * Hn + h] = f2bf(acc[nt][reg] * scale);
        }
    }
}

// ---------------------------------------------------------------------------
// Causal flash attention, bf16 MFMA.  grid 256 (b x 64 qtiles), block 256.
// 32 q-rows/block; 4 waves = 2 row-groups x 2 key-parities (even/odd 64-key
// tiles) -> halves causal critical path.  Online softmax in D-frag layout,
// P via per-wave LDS (wave-internal, in-order DS pipe).  V staged transposed.
// Flash-merge of parity partials via SoA LDS slab at the end.
// ---------------------------------------------------------------------------
__global__ __launch_bounds__(256) void attn(
    const u16* __restrict__ qb, const u16* __restrict__ kb,
    const u16* __restrict__ vb, float* __restrict__ out)
{
    __shared__ u16 Ks[2][64 * 72];
    __shared__ u16 VTs[2][64 * 72];
    __shared__ u16 Pl[4][16 * 72];

    const int tid  = threadIdx.x;
    const int lane = tid & 63;
    const int w    = tid >> 6;
    const int g    = w >> 1;       // row-group 0/1
    const int p    = w & 1;        // key-tile parity
    const int l15  = lane & 15;
    const int lg   = lane >> 4;

    const int b   = blockIdx.x >> 6;
    const int qt  = blockIdx.x & 63;
    const int t0  = qt * 32;
    const int wr0 = t0 + g * 16;
    const int nkt = ((t0 + 31) >> 6) + 1;
    const int S   = (nkt + 1) >> 1;

    const size_t kvbase = (size_t)b * Tn * Hn;

    // Q fragments (q pre-scaled in projection)
    bf16x8 qf[2];
    {
        const u16* qrow = qb + ((size_t)(b * Tn + wr0 + l15)) * Hn;
        qf[0] = *reinterpret_cast<const bf16x8*>(&qrow[(lg << 3)]);
        qf[1] = *reinterpret_cast<const bf16x8*>(&qrow[32 + (lg << 3)]);
    }

    f32x4 o[4];
    float m[4], ls[4];
#pragma unroll
    for (int nt = 0; nt < 4; ++nt)
#pragma unroll
        for (int r = 0; r < 4; ++r) o[nt][r] = 0.f;
#pragma unroll
    for (int r = 0; r < 4; ++r) { m[r] = -INFINITY; ls[r] = 0.f; }

    for (int s = 0; s < S; ++s) {
        const int kt0 = 2 * s, kt1 = 2 * s + 1;
        // ---- stage even tile ----
#pragma unroll
        for (int i = 0; i < 2; ++i) {
            int c = tid + 256 * i;                  // 0..511 chunks of 8 bf16
            int r = c >> 3, c8 = (c & 7) << 3;
            *reinterpret_cast<u16x8*>(&Ks[0][r * 72 + c8]) =
                *reinterpret_cast<const u16x8*>(&kb[kvbase + (size_t)(kt0 * 64 + r) * Hn + c8]);
        }
#pragma unroll
        for (int i = 0; i < 2; ++i) {
            int c = tid + 256 * i;
            int k = c & 63, d0 = (c >> 6) << 3;
            u16x8 v = *reinterpret_cast<const u16x8*>(&vb[kvbase + (size_t)(kt0 * 64 + k) * Hn + d0]);
#pragma unroll
            for (int j = 0; j < 8; ++j) VTs[0][(d0 + j) * 72 + k] = v[j];
        }
        // ---- stage odd tile ----
        if (kt1 < nkt) {
#pragma unroll
            for (int i = 0; i < 2; ++i) {
                int c = tid + 256 * i;
                int r = c >> 3, c8 = (c & 7) << 3;
                *reinterpret_cast<u16x8*>(&Ks[1][r * 72 + c8]) =
                    *reinterpret_cast<const u16x8*>(&kb[kvbase + (size_t)(kt1 * 64 + r) * Hn + c8]);
            }
#pragma unroll
            for (int i = 0; i < 2; ++i) {
                int c = tid + 256 * i;
                int k = c & 63, d0 = (c >> 6) << 3;
                u16x8 v = *reinterpret_cast<const u16x8*>(&vb[kvbase + (size_t)(kt1 * 64 + k) * Hn + d0]);
#pragma unroll
                for (int j = 0; j < 8; ++j) VTs[1][(d0 + j) * 72 + k] = v[j];
            }
        }
        __syncthreads();

        const int mykt = 2 * s + p;
        if (mykt < nkt) {
            // QK^T
            f32x4 sf[4];
#pragma unroll
            for (int nt = 0; nt < 4; ++nt)
#pragma unroll
                for (int r = 0; r < 4; ++r) sf[nt][r] = 0.f;
#pragma unroll
            for (int kc = 0; kc < 2; ++kc) {
#pragma unroll
                for (int nt = 0; nt < 4; ++nt) {
                    bf16x8 kf = *reinterpret_cast<const bf16x8*>(
                        &Ks[p][(nt * 16 + l15) * 72 + kc * 32 + (lg << 3)]);
                    sf[nt] = __builtin_amdgcn_mfma_f32_16x16x32_bf16(qf[kc], kf, sf[nt], 0, 0, 0);
                }
            }
            // causal mask (only needed on diagonal tiles)
            if (mykt * 64 + 63 > wr0) {
#pragma unroll
                for (int nt = 0; nt < 4; ++nt) {
                    int kg = mykt * 64 + nt * 16 + l15;
#pragma unroll
                    for (int reg = 0; reg < 4; ++reg) {
                        int tq = wr0 + (lg << 2) + reg;
                        if (kg > tq) sf[nt][reg] = -INFINITY;
                    }
                }
            }
            // online softmax per row (reg), 16-lane butterflies
            float pv[4][4];
#pragma unroll
            for (int reg = 0; reg < 4; ++reg) {
                float tm = fmaxf(fmaxf(sf[0][reg], sf[1][reg]),
                                 fmaxf(sf[2][reg], sf[3][reg]));
#pragma unroll
                for (int off = 1; off < 16; off <<= 1)
                    tm = fmaxf(tm, __shfl_xor(tm, off, 64));
                float nm = fmaxf(m[reg], tm);
                float al = __expf(m[reg] - nm);
                float rs = 0.f;
#pragma unroll
                for (int nt = 0; nt < 4; ++nt) {
                    pv[nt][reg] = __expf(sf[nt][reg] - nm);
                    rs += pv[nt][reg];
                }
#pragma unroll
                for (int off = 1; off < 16; off <<= 1)
                    rs += __shfl_xor(rs, off, 64);
                ls[reg] = ls[reg] * al + rs;
                m[reg]  = nm;
#pragma unroll
                for (int nt = 0; nt < 4; ++nt) o[nt][reg] *= al;
            }
            // store P (bf16) to per-wave LDS
#pragma unroll
            for (int nt = 0; nt < 4; ++nt)
#pragma unroll
                for (int reg = 0; reg < 4; ++reg)
                    Pl[w][((lg << 2) + reg) * 72 + nt * 16 + l15] = f2bf(pv[nt][reg]);
            // PV
#pragma unroll
            for (int kc = 0; kc < 2; ++kc) {
                bf16x8 pa = *reinterpret_cast<const bf16x8*>(
                    &Pl[w][l15 * 72 + kc * 32 + (lg << 3)]);
#pragma unroll
                for (int nt = 0; nt < 4; ++nt) {
                    bf16x8 vf = *reinterpret_cast<const bf16x8*>(
                        &VTs[p][(nt * 16 + l15) * 72 + kc * 32 + (lg << 3)]);
                    o[nt] = __builtin_amdgcn_mfma_f32_16x16x32_bf16(pa, vf, o[nt], 0, 0, 0);
                }
            }
        }
        __syncthreads();
    }

    // ---- merge parity partials (SoA slab reusing Ks) ----
    float* slab = reinterpret_cast<float*>(&Ks[0][0]);
    float* sb = slab + g * (24 * 64);
    if (p == 1) {
#pragma unroll
        for (int nt = 0; nt < 4; ++nt)
#pragma unroll
            for (int reg = 0; reg < 4; ++reg)
                sb[(nt * 4 + reg) * 64 + lane] = o[nt][reg];
#pragma unroll
        for (int reg = 0; reg < 4; ++reg) {
            sb[(16 + reg) * 64 + lane] = m[reg];
            sb[(20 + reg) * 64 + lane] = ls[reg];
        }
    }
    __syncthreads();
    if (p == 0) {
#pragma unroll
        for (int reg = 0; reg < 4; ++reg) {
            float mB = sb[(16 + reg) * 64 + lane];
            float lB = sb[(20 + reg) * 64 + lane];
            float ms = fmaxf(m[reg], mB);
            float aA = __expf(m[reg] - ms);
            float aB = __expf(mB - ms);
            float inv = 1.0f / (aA * ls[reg] + aB * lB);
            int grow = wr0 + (lg << 2) + reg;
            float* orow = out + ((size_t)(b * Tn) + grow) * Hn;
#pragma unroll
            for (int nt = 0; nt < 4; ++nt)
                orow[nt * 16 + l15] =
                    (aA * o[nt][reg] + aB * sb[(nt * 4 + reg) * 64 + lane]) * inv;
        }
    }
}

extern "C" void kernel_launch(void* const* d_in, const int* in_sizes, int n_in,
                              void* d_out, int out_size, void* d_ws, size_t ws_size,
                              hipStream_t stream) {
    const float* x  = (const float*)d_in[0];
    const float* Wk = (const float*)d_in[1];
    const float* Wq = (const float*)d_in[2];
    const float* Wv = (const float*)d_in[3];
    float* out = (float*)d_out;

    const size_t rows = (size_t)4 * Tn;            // 8192
    u16* kbuf = (u16*)d_ws;                        // [8192][64] bf16
    u16* qbuf = kbuf + rows * Hn;
    u16* vbuf = qbuf + rows * Hn;

    qkv_proj<<<128, 512, 0, stream>>>(x, Wk, Wq, Wv, kbuf, qbuf, vbuf);
    attn<<<4 * (Tn / 32), 256, 0, stream>>>(qbuf, kbuf, vbuf, out);
}

// Round 3
// 82.838 us; speedup vs baseline: 3.8488x; 1.1619x over previous
//
#include <hip/hip_runtime.h>
#include <math.h>

#define Tn 2048
#define Cn 1024
#define Hn 64

using u16 = unsigned short;
typedef float f32x4 __attribute__((ext_vector_type(4)));
typedef __bf16 bf16x8 __attribute__((ext_vector_type(8)));
typedef u16 u16x8 __attribute__((ext_vector_type(8)));
typedef u16 u16x4 __attribute__((ext_vector_type(4)));

__device__ __forceinline__ u16 f2bf(float f) {
    return __builtin_bit_cast(u16, static_cast<__bf16>(f));
}

// ---------------------------------------------------------------------------
// W pack: [Wk|Wq|Wv] f32 [64][1024] each  ->  bf16 fragment-order buffer
//   wp[((n16*32 + kc)*64 + lane)*8 + j] = W[n16*16 + (lane&15)][kc*32 + (lane>>4)*8 + j]
// (q rows, n16 4..7, pre-scaled by C^-0.5 = 1/32).  24576 slots x 8 elems.
// ---------------------------------------------------------------------------
__global__ __launch_bounds__(256) void wpack_kernel(
    const float* __restrict__ Wk, const float* __restrict__ Wq,
    const float* __restrict__ Wv, u16* __restrict__ wp)
{
    int slot = blockIdx.x * 256 + threadIdx.x;   // 0..24575
    int n16  = slot >> 11;                       // /(32*64)
    int rem  = slot & 2047;
    int kc   = rem >> 6;
    int lane = rem & 63;
    int l15 = lane & 15, lg = lane >> 4;
    int col = n16 * 16 + l15;                    // 0..191
    const float* __restrict__ Wm = (col < 64) ? Wk : (col < 128) ? Wq : Wv;
    float sc = (col >= 64 && col < 128) ? 0.03125f : 1.0f;
    const float* src = &Wm[(size_t)(col & 63) * Cn + kc * 32 + lg * 8];
    float4 lo = *reinterpret_cast<const float4*>(src);
    float4 hi = *reinterpret_cast<const float4*>(src + 4);
    u16x8 o;
    o[0] = f2bf(lo.x * sc); o[1] = f2bf(lo.y * sc);
    o[2] = f2bf(lo.z * sc); o[3] = f2bf(lo.w * sc);
    o[4] = f2bf(hi.x * sc); o[5] = f2bf(hi.y * sc);
    o[6] = f2bf(hi.z * sc); o[7] = f2bf(hi.w * sc);
    *reinterpret_cast<u16x8*>(&wp[(size_t)slot * 8]) = o;
}

// ---------------------------------------------------------------------------
// QKV projection: barrier-free streaming bf16 MFMA GEMM.
// 1024 waves (grid 256 x 4 waves); wave = 16 rows x 96 cols (col-half ch).
// Per K-step (32): 2 float4 x-loads (cvt in reg) + 6 B-frag loads + 6 MFMA.
// No LDS, no __syncthreads; latency hidden by unroll-4 ILP.
// ---------------------------------------------------------------------------
__global__ __launch_bounds__(256, 2) void qkv_proj(
    const float* __restrict__ x, const u16* __restrict__ wp,
    u16* __restrict__ kb, u16* __restrict__ qb, u16* __restrict__ vb)
{
    const int tid  = threadIdx.x;
    const int lane = tid & 63;
    const int w    = tid >> 6;
    const int wave = blockIdx.x * 4 + w;
    const int rg   = wave >> 1;          // 0..511, 16-row group
    const int ch   = wave & 1;           // col half (96)
    const int l15  = lane & 15;
    const int lg   = lane >> 4;

    const float* __restrict__ xrow = x + (size_t)(rg * 16 + l15) * Cn;
    const u16* __restrict__ wbase  = wp + (size_t)ch * 6 * 32 * 64 * 8;

    f32x4 acc[6];
#pragma unroll
    for (int nt = 0; nt < 6; ++nt)
#pragma unroll
        for (int r = 0; r < 4; ++r) acc[nt][r] = 0.f;

#pragma unroll 4
    for (int kc = 0; kc < 32; ++kc) {
        float4 lo = *reinterpret_cast<const float4*>(&xrow[kc * 32 + lg * 8]);
        float4 hi = *reinterpret_cast<const float4*>(&xrow[kc * 32 + lg * 8 + 4]);
        bf16x8 a;
        a[0] = (__bf16)lo.x; a[1] = (__bf16)lo.y;
        a[2] = (__bf16)lo.z; a[3] = (__bf16)lo.w;
        a[4] = (__bf16)hi.x; a[5] = (__bf16)hi.y;
        a[6] = (__bf16)hi.z; a[7] = (__bf16)hi.w;
#pragma unroll
        for (int nt = 0; nt < 6; ++nt) {
            bf16x8 bfr = *reinterpret_cast<const bf16x8*>(
                &wbase[(size_t)((nt * 32 + kc) * 64 + lane) * 8]);
            acc[nt] = __builtin_amdgcn_mfma_f32_16x16x32_bf16(a, bfr, acc[nt], 0, 0, 0);
        }
    }

    // D layout: col = l15, row-in-tile = lg*4 + reg
#pragma unroll
    for (int nt = 0; nt < 6; ++nt) {
        int col0 = ch * 96 + nt * 16;
        int mat  = col0 >> 6;
        u16* __restrict__ ob = (mat == 0) ? kb : (mat == 1) ? qb : vb;
        int h = (col0 & 63) + l15;
#pragma unroll
        for (int reg = 0; reg < 4; ++reg) {
            int grow = rg * 16 + (lg << 2) + reg;
            ob[(size_t)grow * Hn + h] = f2bf(acc[nt][reg]);
        }
    }
}

// ---------------------------------------------------------------------------
// Causal flash attention (unchanged from R1; bf16 MFMA, 2 row-groups x 2
// key-parities, online softmax, parity merge in LDS).
// ---------------------------------------------------------------------------
__global__ __launch_bounds__(256) void attn(
    const u16* __restrict__ qb, const u16* __restrict__ kb,
    const u16* __restrict__ vb, float* __restrict__ out)
{
    __shared__ u16 Ks[2][64 * 72];
    __shared__ u16 VTs[2][64 * 72];
    __shared__ u16 Pl[4][16 * 72];

    const int tid  = threadIdx.x;
    const int lane = tid & 63;
    const int w    = tid >> 6;
    const int g    = w >> 1;
    const int p    = w & 1;
    const int l15  = lane & 15;
    const int lg   = lane >> 4;

    const int b   = blockIdx.x >> 6;
    const int qt  = blockIdx.x & 63;
    const int t0  = qt * 32;
    const int wr0 = t0 + g * 16;
    const int nkt = ((t0 + 31) >> 6) + 1;
    const int S   = (nkt + 1) >> 1;

    const size_t kvbase = (size_t)b * Tn * Hn;

    bf16x8 qf[2];
    {
        const u16* qrow = qb + ((size_t)(b * Tn + wr0 + l15)) * Hn;
        qf[0] = *reinterpret_cast<const bf16x8*>(&qrow[(lg << 3)]);
        qf[1] = *reinterpret_cast<const bf16x8*>(&qrow[32 + (lg << 3)]);
    }

    f32x4 o[4];
    float m[4], ls[4];
#pragma unroll
    for (int nt = 0; nt < 4; ++nt)
#pragma unroll
        for (int r = 0; r < 4; ++r) o[nt][r] = 0.f;
#pragma unroll
    for (int r = 0; r < 4; ++r) { m[r] = -INFINITY; ls[r] = 0.f; }

    for (int s = 0; s < S; ++s) {
        const int kt0 = 2 * s, kt1 = 2 * s + 1;
#pragma unroll
        for (int i = 0; i < 2; ++i) {
            int c = tid + 256 * i;
            int r = c >> 3, c8 = (c & 7) << 3;
            *reinterpret_cast<u16x8*>(&Ks[0][r * 72 + c8]) =
                *reinterpret_cast<const u16x8*>(&kb[kvbase + (size_t)(kt0 * 64 + r) * Hn + c8]);
        }
#pragma unroll
        for (int i = 0; i < 2; ++i) {
            int c = tid + 256 * i;
            int k = c & 63, d0 = (c >> 6) << 3;
            u16x8 v = *reinterpret_cast<const u16x8*>(&vb[kvbase + (size_t)(kt0 * 64 + k) * Hn + d0]);
#pragma unroll
            for (int j = 0; j < 8; ++j) VTs[0][(d0 + j) * 72 + k] = v[j];
        }
        if (kt1 < nkt) {
#pragma unroll
            for (int i = 0; i < 2; ++i) {
                int c = tid + 256 * i;
                int r = c >> 3, c8 = (c & 7) << 3;
                *reinterpret_cast<u16x8*>(&Ks[1][r * 72 + c8]) =
                    *reinterpret_cast<const u16x8*>(&kb[kvbase + (size_t)(kt1 * 64 + r) * Hn + c8]);
            }
#pragma unroll
            for (int i = 0; i < 2; ++i) {
                int c = tid + 256 * i;
                int k = c & 63, d0 = (c >> 6) << 3;
                u16x8 v = *reinterpret_cast<const u16x8*>(&vb[kvbase + (size_t)(kt1 * 64 + k) * Hn + d0]);
#pragma unroll
                for (int j = 0; j < 8; ++j) VTs[1][(d0 + j) * 72 + k] = v[j];
            }
        }
        __syncthreads();

        const int mykt = 2 * s + p;
        if (mykt < nkt) {
            f32x4 sf[4];
#pragma unroll
            for (int nt = 0; nt < 4; ++nt)
#pragma unroll
                for (int r = 0; r < 4; ++r) sf[nt][r] = 0.f;
#pragma unroll
            for (int kc = 0; kc < 2; ++kc) {
#pragma unroll
                for (int nt = 0; nt < 4; ++nt) {
                    bf16x8 kf = *reinterpret_cast<const bf16x8*>(
                        &Ks[p][(nt * 16 + l15) * 72 + kc * 32 + (lg << 3)]);
                    sf[nt] = __builtin_amdgcn_mfma_f32_16x16x32_bf16(qf[kc], kf, sf[nt], 0, 0, 0);
                }
            }
            if (mykt * 64 + 63 > wr0) {
#pragma unroll
                for (int nt = 0; nt < 4; ++nt) {
                    int kg = mykt * 64 + nt * 16 + l15;
#pragma unroll
                    for (int reg = 0; reg < 4; ++reg) {
                        int tq = wr0 + (lg << 2) + reg;
                        if (kg > tq) sf[nt][reg] = -INFINITY;
                    }
                }
            }
            float pv[4][4];
#pragma unroll
            for (int reg = 0; reg < 4; ++reg) {
                float tm = fmaxf(fmaxf(sf[0][reg], sf[1][reg]),
                                 fmaxf(sf[2][reg], sf[3][reg]));
#pragma unroll
                for (int off = 1; off < 16; off <<= 1)
                    tm = fmaxf(tm, __shfl_xor(tm, off, 64));
                float nm = fmaxf(m[reg], tm);
                float al = __expf(m[reg] - nm);
                float rs = 0.f;
#pragma unroll
                for (int nt = 0; nt < 4; ++nt) {
                    pv[nt][reg] = __expf(sf[nt][reg] - nm);
                    rs += pv[nt][reg];
                }
#pragma unroll
                for (int off = 1; off < 16; off <<= 1)
                    rs += __shfl_xor(rs, off, 64);
                ls[reg] = ls[reg] * al + rs;
                m[reg]  = nm;
#pragma unroll
                for (int nt = 0; nt < 4; ++nt) o[nt][reg] *= al;
            }
#pragma unroll
            for (int nt = 0; nt < 4; ++nt)
#pragma unroll
                for (int reg = 0; reg < 4; ++reg)
                    Pl[w][((lg << 2) + reg) * 72 + nt * 16 + l15] = f2bf(pv[nt][reg]);
#pragma unroll
            for (int kc = 0; kc < 2; ++kc) {
                bf16x8 pa = *reinterpret_cast<const bf16x8*>(
                    &Pl[w][l15 * 72 + kc * 32 + (lg << 3)]);
#pragma unroll
                for (int nt = 0; nt < 4; ++nt) {
                    bf16x8 vf = *reinterpret_cast<const bf16x8*>(
                        &VTs[p][(nt * 16 + l15) * 72 + kc * 32 + (lg << 3)]);
                    o[nt] = __builtin_amdgcn_mfma_f32_16x16x32_bf16(pa, vf, o[nt], 0, 0, 0);
                }
            }
        }
        __syncthreads();
    }

    float* slab = reinterpret_cast<float*>(&Ks[0][0]);
    float* sb = slab + g * (24 * 64);
    if (p == 1) {
#pragma unroll
        for (int nt = 0; nt < 4; ++nt)
#pragma unroll
            for (int reg = 0; reg < 4; ++reg)
                sb[(nt * 4 + reg) * 64 + lane] = o[nt][reg];
#pragma unroll
        for (int reg = 0; reg < 4; ++reg) {
            sb[(16 + reg) * 64 + lane] = m[reg];
            sb[(20 + reg) * 64 + lane] = ls[reg];
        }
    }
    __syncthreads();
    if (p == 0) {
#pragma unroll
        for (int reg = 0; reg < 4; ++reg) {
            float mB = sb[(16 + reg) * 64 + lane];
            float lB = sb[(20 + reg) * 64 + lane];
            float ms = fmaxf(m[reg], mB);
            float aA = __expf(m[reg] - ms);
            float aB = __expf(mB - ms);
            float inv = 1.0f / (aA * ls[reg] + aB * lB);
            int grow = wr0 + (lg << 2) + reg;
            float* orow = out + ((size_t)(b * Tn) + grow) * Hn;
#pragma unroll
            for (int nt = 0; nt < 4; ++nt)
                orow[nt * 16 + l15] =
                    (aA * o[nt][reg] + aB * sb[(nt * 4 + reg) * 64 + lane]) * inv;
        }
    }
}

extern "C" void kernel_launch(void* const* d_in, const int* in_sizes, int n_in,
                              void* d_out, int out_size, void* d_ws, size_t ws_size,
                              hipStream_t stream) {
    const float* x  = (const float*)d_in[0];
    const float* Wk = (const float*)d_in[1];
    const float* Wq = (const float*)d_in[2];
    const float* Wv = (const float*)d_in[3];
    float* out = (float*)d_out;

    const size_t rows = (size_t)4 * Tn;            // 8192
    u16* kbuf = (u16*)d_ws;                        // [8192][64] bf16
    u16* qbuf = kbuf + rows * Hn;
    u16* vbuf = qbuf + rows * Hn;
    u16* wpk  = vbuf + rows * Hn;                  // 196608 u16 = 384KB

    wpack_kernel<<<96, 256, 0, stream>>>(Wk, Wq, Wv, wpk);
    qkv_proj<<<256, 256, 0, stream>>>(x, wpk, kbuf, qbuf, vbuf);
    attn<<<4 * (Tn / 32), 256, 0, stream>>>(qbuf, kbuf, vbuf, out);
}

// Round 4
// 68.906 us; speedup vs baseline: 4.6269x; 1.2022x over previous
//
#include <hip/hip_runtime.h>
#include <math.h>

#define Tn 2048
#define Cn 1024
#define Hn 64

using u16 = unsigned short;
typedef float f32x4 __attribute__((ext_vector_type(4)));
typedef __bf16 bf16x8 __attribute__((ext_vector_type(8)));
typedef u16 u16x8 __attribute__((ext_vector_type(8)));
typedef u16 u16x4 __attribute__((ext_vector_type(4)));

__device__ __forceinline__ u16 f2bf(float f) {
    return __builtin_bit_cast(u16, static_cast<__bf16>(f));
}

// ---------------------------------------------------------------------------
// W pack: [Wk|Wq|Wv] f32 -> bf16 in MFMA B-fragment order.
// wp[(n16*32 + kc)*64 + lane] (x8 elems) = W[n16*16 + (lane&15)][kc*32+(lane>>4)*8 ..]
// Wq rows pre-scaled by C^-0.5 = 1/32.
// ---------------------------------------------------------------------------
__global__ __launch_bounds__(256) void wpack_kernel(
    const float* __restrict__ Wk, const float* __restrict__ Wq,
    const float* __restrict__ Wv, u16* __restrict__ wp)
{
    int slot = blockIdx.x * 256 + threadIdx.x;   // 0..24575
    int n16  = slot >> 11;
    int rem  = slot & 2047;
    int kc   = rem >> 6;
    int lane = rem & 63;
    int l15 = lane & 15, lg = lane >> 4;
    int col = n16 * 16 + l15;                    // 0..191
    const float* __restrict__ Wm = (col < 64) ? Wk : (col < 128) ? Wq : Wv;
    float sc = (col >= 64 && col < 128) ? 0.03125f : 1.0f;
    const float* src = &Wm[(size_t)(col & 63) * Cn + kc * 32 + lg * 8];
    float4 lo = *reinterpret_cast<const float4*>(src);
    float4 hi = *reinterpret_cast<const float4*>(src + 4);
    u16x8 o;
    o[0] = f2bf(lo.x * sc); o[1] = f2bf(lo.y * sc);
    o[2] = f2bf(lo.z * sc); o[3] = f2bf(lo.w * sc);
    o[4] = f2bf(hi.x * sc); o[5] = f2bf(hi.y * sc);
    o[6] = f2bf(hi.z * sc); o[7] = f2bf(hi.w * sc);
    *reinterpret_cast<u16x8*>(&wp[(size_t)slot * 8]) = o;
}

// ---------------------------------------------------------------------------
// QKV projection, split-K 2-way.  grid 512 (= 256 row-tiles x 2 K-halves),
// block 256 (4 waves = 2 rowgroups x 2 col-halves).  BM=32, BK=64, 8 K-steps.
// x staged coalesced -> padded LDS f32 [32][68]; double-buffered with
// async-split staging (global loads issued before compute, ds_write after).
// W fragments direct from packed wp (L2/L1 resident).  f32 partial output.
// ---------------------------------------------------------------------------
__global__ __launch_bounds__(256) void qkv_proj(
    const float* __restrict__ x, const u16* __restrict__ wp,
    float* __restrict__ part)
{
    __shared__ float xs[2][32 * 68];

    const int tid  = threadIdx.x;
    const int lane = tid & 63;
    const int wv   = tid >> 6;        // 0..3
    const int wr   = (wv & 1) * 16;   // row base in tile
    const int ch   = wv >> 1;         // col half (96)
    const int l15  = lane & 15;
    const int lg   = lane >> 4;

    const int kh   = blockIdx.x & 1;          // K half
    const int rt   = blockIdx.x >> 1;         // row tile 0..255
    const int row0 = rt * 32;
    const int kbase = kh * 512;

    // staging slots: thread handles slots tid and tid+256 (512 float4 = 32x64 f32)
    const int sr0 = tid >> 4,        sc0 = (tid & 15) << 2;
    const int sr1 = (tid + 256) >> 4, sc1c = ((tid + 256) & 15) << 2;

    f32x4 acc[6];
#pragma unroll
    for (int nt = 0; nt < 6; ++nt)
#pragma unroll
        for (int r = 0; r < 4; ++r) acc[nt][r] = 0.f;

    // prologue: stage step 0 into buf 0
    float4 gA = *reinterpret_cast<const float4*>(
        &x[(size_t)(row0 + sr0) * Cn + kbase + sc0]);
    float4 gB = *reinterpret_cast<const float4*>(
        &x[(size_t)(row0 + sr1) * Cn + kbase + sc1c]);
    *reinterpret_cast<float4*>(&xs[0][sr0 * 68 + sc0]) = gA;
    *reinterpret_cast<float4*>(&xs[0][sr1 * 68 + sc1c]) = gB;
    __syncthreads();

    for (int ks = 0; ks < 8; ++ks) {
        const int cur = ks & 1;
        if (ks < 7) {   // issue next-step global loads early (latency hides under MFMA)
            gA = *reinterpret_cast<const float4*>(
                &x[(size_t)(row0 + sr0) * Cn + kbase + (ks + 1) * 64 + sc0]);
            gB = *reinterpret_cast<const float4*>(
                &x[(size_t)(row0 + sr1) * Cn + kbase + (ks + 1) * 64 + sc1c]);
        }
#pragma unroll
        for (int kc2 = 0; kc2 < 2; ++kc2) {
            const float* ap = &xs[cur][(wr + l15) * 68 + kc2 * 32 + (lg << 3)];
            f32x4 a0 = *reinterpret_cast<const f32x4*>(ap);
            f32x4 a1 = *reinterpret_cast<const f32x4*>(ap + 4);
            bf16x8 a;
            a[0] = (__bf16)a0[0]; a[1] = (__bf16)a0[1];
            a[2] = (__bf16)a0[2]; a[3] = (__bf16)a0[3];
            a[4] = (__bf16)a1[0]; a[5] = (__bf16)a1[1];
            a[6] = (__bf16)a1[2]; a[7] = (__bf16)a1[3];
            const int kcg = kh * 16 + ks * 2 + kc2;
#pragma unroll
            for (int nt = 0; nt < 6; ++nt) {
                bf16x8 bfr = *reinterpret_cast<const bf16x8*>(
                    &wp[(size_t)(((ch * 6 + nt) * 32 + kcg) * 64 + lane) * 8]);
                acc[nt] = __builtin_amdgcn_mfma_f32_16x16x32_bf16(a, bfr, acc[nt], 0, 0, 0);
            }
        }
        if (ks < 7) {
            *reinterpret_cast<float4*>(&xs[cur ^ 1][sr0 * 68 + sc0]) = gA;
            *reinterpret_cast<float4*>(&xs[cur ^ 1][sr1 * 68 + sc1c]) = gB;
        }
        __syncthreads();
    }

    float* __restrict__ pb = part + (size_t)kh * 8192 * 192;
#pragma unroll
    for (int nt = 0; nt < 6; ++nt) {
        int colc = ch * 96 + nt * 16 + l15;
#pragma unroll
        for (int reg = 0; reg < 4; ++reg) {
            int grow = row0 + wr + (lg << 2) + reg;
            pb[(size_t)grow * 192 + colc] = acc[nt][reg];
        }
    }
}

// ---------------------------------------------------------------------------
// Merge K-half partials -> bf16 k/q/v buffers.  grid 768, block 256.
// ---------------------------------------------------------------------------
__global__ __launch_bounds__(256) void proj_merge(
    const float* __restrict__ part,
    u16* __restrict__ kb, u16* __restrict__ qb, u16* __restrict__ vb)
{
    int gid = blockIdx.x * 256 + threadIdx.x;    // 0..196607
    int row = gid / 24;
    int col = (gid % 24) * 8;
    const float* p0 = part + (size_t)row * 192 + col;
    const float* p1 = p0 + (size_t)8192 * 192;
    f32x4 a0 = *reinterpret_cast<const f32x4*>(p0);
    f32x4 a1 = *reinterpret_cast<const f32x4*>(p0 + 4);
    f32x4 b0 = *reinterpret_cast<const f32x4*>(p1);
    f32x4 b1 = *reinterpret_cast<const f32x4*>(p1 + 4);
    u16x8 o;
    o[0] = f2bf(a0[0] + b0[0]); o[1] = f2bf(a0[1] + b0[1]);
    o[2] = f2bf(a0[2] + b0[2]); o[3] = f2bf(a0[3] + b0[3]);
    o[4] = f2bf(a1[0] + b1[0]); o[5] = f2bf(a1[1] + b1[1]);
    o[6] = f2bf(a1[2] + b1[2]); o[7] = f2bf(a1[3] + b1[3]);
    int mat = col >> 6;
    u16* __restrict__ ob = (mat == 0) ? kb : (mat == 1) ? qb : vb;
    *reinterpret_cast<u16x8*>(&ob[(size_t)row * 64 + (col & 63)]) = o;
}

// ---------------------------------------------------------------------------
// Causal flash attention, split-KV.  Work unit = (b, 32-row qtile, 256-key
// chunk); 1152 uniform blocks (4.5/CU).  Block: 4 waves = 2 rowgroups x 2
// key-parities over the chunk's 4 64-key tiles.  In-block parity merge, then
// write f32 (O, m, l) partial; attn_merge combines chunks online.
// ---------------------------------------------------------------------------
__global__ __launch_bounds__(256) void attn(
    const u16* __restrict__ qb, const u16* __restrict__ kb,
    const u16* __restrict__ vb, float* __restrict__ Opart,
    float* __restrict__ mlb)
{
    __shared__ u16 Ks[2][64 * 72];
    __shared__ u16 VTs[2][64 * 72];
    __shared__ u16 Pl[4][16 * 72];

    const int tid  = threadIdx.x;
    const int lane = tid & 63;
    const int w    = tid >> 6;
    const int g    = w >> 1;
    const int p    = w & 1;
    const int l15  = lane & 15;
    const int lg   = lane >> 4;

    // decode (b, qt, c) from uniform work list: per batch, qt-group gq has
    // 8 qtiles x (gq+1) chunks; cum(gq) = 4*gq*(gq+1).
    const int bid = blockIdx.x;
    const int b = bid / 288;
    const int r = bid % 288;
    int gq = (int)((sqrtf((float)r + 1.0f) - 1.0f) * 0.5f);
    while (4 * (gq + 1) * (gq + 2) <= r) ++gq;
    while (4 * gq * (gq + 1) > r) --gq;
    const int rr = r - 4 * gq * (gq + 1);
    const int qt = gq * 8 + rr / (gq + 1);
    const int c  = rr % (gq + 1);

    const int t0  = qt * 32;
    const int wr0 = t0 + g * 16;
    const int nkt = ((t0 + 31) >> 6) + 1;
    const size_t kvbase = (size_t)b * Tn * Hn;

    bf16x8 qf[2];
    {
        const u16* qrow = qb + ((size_t)(b * Tn + wr0 + l15)) * Hn;
        qf[0] = *reinterpret_cast<const bf16x8*>(&qrow[(lg << 3)]);
        qf[1] = *reinterpret_cast<const bf16x8*>(&qrow[32 + (lg << 3)]);
    }

    f32x4 o[4];
    float m[4], ls[4];
#pragma unroll
    for (int nt = 0; nt < 4; ++nt)
#pragma unroll
        for (int rg = 0; rg < 4; ++rg) o[nt][rg] = 0.f;
#pragma unroll
    for (int rg = 0; rg < 4; ++rg) { m[rg] = -INFINITY; ls[rg] = 0.f; }

    for (int s = 0; s < 2; ++s) {
        const int kt0 = c * 4 + 2 * s, kt1 = kt0 + 1;
        if (kt0 < nkt) {
#pragma unroll
            for (int i = 0; i < 2; ++i) {
                int cc = tid + 256 * i;
                int rr2 = cc >> 3, c8 = (cc & 7) << 3;
                *reinterpret_cast<u16x8*>(&Ks[0][rr2 * 72 + c8]) =
                    *reinterpret_cast<const u16x8*>(&kb[kvbase + (size_t)(kt0 * 64 + rr2) * Hn + c8]);
            }
#pragma unroll
            for (int i = 0; i < 2; ++i) {
                int cc = tid + 256 * i;
                int k = cc & 63, d0 = (cc >> 6) << 3;
                u16x8 v = *reinterpret_cast<const u16x8*>(&vb[kvbase + (size_t)(kt0 * 64 + k) * Hn + d0]);
#pragma unroll
                for (int j = 0; j < 8; ++j) VTs[0][(d0 + j) * 72 + k] = v[j];
            }
        }
        if (kt1 < nkt) {
#pragma unroll
            for (int i = 0; i < 2; ++i) {
                int cc = tid + 256 * i;
                int rr2 = cc >> 3, c8 = (cc & 7) << 3;
                *reinterpret_cast<u16x8*>(&Ks[1][rr2 * 72 + c8]) =
                    *reinterpret_cast<const u16x8*>(&kb[kvbase + (size_t)(kt1 * 64 + rr2) * Hn + c8]);
            }
#pragma unroll
            for (int i = 0; i < 2; ++i) {
                int cc = tid + 256 * i;
                int k = cc & 63, d0 = (cc >> 6) << 3;
                u16x8 v = *reinterpret_cast<const u16x8*>(&vb[kvbase + (size_t)(kt1 * 64 + k) * Hn + d0]);
#pragma unroll
                for (int j = 0; j < 8; ++j) VTs[1][(d0 + j) * 72 + k] = v[j];
            }
        }
        __syncthreads();

        const int mykt = kt0 + p;
        if (mykt < nkt) {
            f32x4 sf[4];
#pragma unroll
            for (int nt = 0; nt < 4; ++nt)
#pragma unroll
                for (int rg = 0; rg < 4; ++rg) sf[nt][rg] = 0.f;
#pragma unroll
            for (int kc = 0; kc < 2; ++kc) {
#pragma unroll
                for (int nt = 0; nt < 4; ++nt) {
                    bf16x8 kf = *reinterpret_cast<const bf16x8*>(
                        &Ks[p][(nt * 16 + l15) * 72 + kc * 32 + (lg << 3)]);
                    sf[nt] = __builtin_amdgcn_mfma_f32_16x16x32_bf16(qf[kc], kf, sf[nt], 0, 0, 0);
                }
            }
            if (mykt * 64 + 63 > wr0) {
#pragma unroll
                for (int nt = 0; nt < 4; ++nt) {
                    int kg = mykt * 64 + nt * 16 + l15;
#pragma unroll
                    for (int reg = 0; reg < 4; ++reg) {
                        int tq = wr0 + (lg << 2) + reg;
                        if (kg > tq) sf[nt][reg] = -INFINITY;
                    }
                }
            }
            float pv[4][4];
#pragma unroll
            for (int reg = 0; reg < 4; ++reg) {
                float tm = fmaxf(fmaxf(sf[0][reg], sf[1][reg]),
                                 fmaxf(sf[2][reg], sf[3][reg]));
#pragma unroll
                for (int off = 1; off < 16; off <<= 1)
                    tm = fmaxf(tm, __shfl_xor(tm, off, 64));
                float nm = fmaxf(m[reg], tm);
                float al = __expf(m[reg] - nm);
                float rs = 0.f;
#pragma unroll
                for (int nt = 0; nt < 4; ++nt) {
                    pv[nt][reg] = __expf(sf[nt][reg] - nm);
                    rs += pv[nt][reg];
                }
#pragma unroll
                for (int off = 1; off < 16; off <<= 1)
                    rs += __shfl_xor(rs, off, 64);
                ls[reg] = ls[reg] * al + rs;
                m[reg]  = nm;
#pragma unroll
                for (int nt = 0; nt < 4; ++nt) o[nt][reg] *= al;
            }
#pragma unroll
            for (int nt = 0; nt < 4; ++nt)
#pragma unroll
                for (int reg = 0; reg < 4; ++reg)
                    Pl[w][((lg << 2) + reg) * 72 + nt * 16 + l15] = f2bf(pv[nt][reg]);
#pragma unroll
            for (int kc = 0; kc < 2; ++kc) {
                bf16x8 pa = *reinterpret_cast<const bf16x8*>(
                    &Pl[w][l15 * 72 + kc * 32 + (lg << 3)]);
#pragma unroll
                for (int nt = 0; nt < 4; ++nt) {
                    bf16x8 vf = *reinterpret_cast<const bf16x8*>(
                        &VTs[p][(nt * 16 + l15) * 72 + kc * 32 + (lg << 3)]);
                    o[nt] = __builtin_amdgcn_mfma_f32_16x16x32_bf16(pa, vf, o[nt], 0, 0, 0);
                }
            }
        }
        __syncthreads();
    }

    // in-block parity merge -> f32 partial (unnormalized O, m, l)
    float* slab = reinterpret_cast<float*>(&Ks[0][0]);
    float* sb = slab + g * (24 * 64);
    if (p == 1) {
#pragma unroll
        for (int nt = 0; nt < 4; ++nt)
#pragma unroll
            for (int reg = 0; reg < 4; ++reg)
                sb[(nt * 4 + reg) * 64 + lane] = o[nt][reg];
#pragma unroll
        for (int reg = 0; reg < 4; ++reg) {
            sb[(16 + reg) * 64 + lane] = m[reg];
            sb[(20 + reg) * 64 + lane] = ls[reg];
        }
    }
    __syncthreads();
    if (p == 0) {
        const size_t pidx = (size_t)(b * 64 + qt) * 8 + c;
        float* __restrict__ ob = Opart + pidx * 2048;
#pragma unroll
        for (int reg = 0; reg < 4; ++reg) {
            float mB = sb[(16 + reg) * 64 + lane];
            float lB = sb[(20 + reg) * 64 + lane];
            float ms = fmaxf(m[reg], mB);
            float aA = __expf(m[reg] - ms);
            float aB = __expf(mB - ms);
            int row32 = g * 16 + (lg << 2) + reg;
            if (l15 == 0) {
                float* mlp = mlb + pidx * 64 + row32 * 2;
                mlp[0] = ms;
                mlp[1] = aA * ls[reg] + aB * lB;
            }
#pragma unroll
            for (int nt = 0; nt < 4; ++nt)
                ob[row32 * 64 + nt * 16 + l15] =
                    aA * o[nt][reg] + aB * sb[(nt * 4 + reg) * 64 + lane];
        }
    }
}

// ---------------------------------------------------------------------------
// Combine KV-chunk partials online.  grid 256 (= b x qt), block 256.
// Thread: one (row, 8-dim slice).
// ---------------------------------------------------------------------------
__global__ __launch_bounds__(256) void attn_merge(
    const float* __restrict__ Opart, const float* __restrict__ mlb,
    float* __restrict__ out)
{
    const int bid = blockIdx.x;
    const int b = bid >> 6, qt = bid & 63;
    const int nch = (qt >> 3) + 1;
    const int t = threadIdx.x;
    const int row = t >> 3, d0 = (t & 7) << 3;
    const size_t pbase = (size_t)(b * 64 + qt) * 8;

    float m = -INFINITY, l = 0.f;
    f32x4 O0 = {0.f, 0.f, 0.f, 0.f}, O1 = {0.f, 0.f, 0.f, 0.f};
    for (int cc = 0; cc < nch; ++cc) {
        const float* mlp = mlb + (pbase + cc) * 64 + row * 2;
        float mc = mlp[0], lc = mlp[1];
        float nm = fmaxf(m, mc);
        float a  = __expf(m - nm);
        float ac = __expf(mc - nm);
        const float* op = Opart + (pbase + cc) * 2048 + row * 64 + d0;
        f32x4 c0 = *reinterpret_cast<const f32x4*>(op);
        f32x4 c1 = *reinterpret_cast<const f32x4*>(op + 4);
        O0 = O0 * a + c0 * ac;
        O1 = O1 * a + c1 * ac;
        l  = l * a + lc * ac;
        m  = nm;
    }
    float inv = 1.f / l;
    float* orow = out + ((size_t)(b * Tn + qt * 32 + row)) * Hn + d0;
    *reinterpret_cast<f32x4*>(orow)     = O0 * inv;
    *reinterpret_cast<f32x4*>(orow + 4) = O1 * inv;
}

extern "C" void kernel_launch(void* const* d_in, const int* in_sizes, int n_in,
                              void* d_out, int out_size, void* d_ws, size_t ws_size,
                              hipStream_t stream) {
    const float* x  = (const float*)d_in[0];
    const float* Wk = (const float*)d_in[1];
    const float* Wq = (const float*)d_in[2];
    const float* Wv = (const float*)d_in[3];
    float* out = (float*)d_out;

    const size_t rows = (size_t)4 * Tn;            // 8192
    u16* kbuf = (u16*)d_ws;                        // [8192][64] bf16
    u16* qbuf = kbuf + rows * Hn;
    u16* vbuf = qbuf + rows * Hn;
    u16* wpk  = vbuf + rows * Hn;                  // 196608 u16
    float* part  = (float*)(wpk + 196608);         // [2][8192][192] f32
    float* Opart = part + (size_t)2 * 8192 * 192;  // [4][64][8][32][64] f32
    float* mlb   = Opart + (size_t)4 * 64 * 8 * 2048;  // [4][64][8][32][2] f32

    wpack_kernel<<<96, 256, 0, stream>>>(Wk, Wq, Wv, wpk);
    qkv_proj<<<512, 256, 0, stream>>>(x, wpk, part);
    proj_merge<<<768, 256, 0, stream>>>(part, kbuf, qbuf, vbuf);
    attn<<<1152, 256, 0, stream>>>(qbuf, kbuf, vbuf, Opart, mlb);
    attn_merge<<<256, 256, 0, stream>>>(Opart, mlb, out);
}

// Round 5
// 47.207 us; speedup vs baseline: 6.7538x; 1.4597x over previous
//
#include <hip/hip_runtime.h>
#include <math.h>

#define Tn 2048
#define Cn 1024
#define Hn 64

using u16 = unsigned short;
typedef float f32x4 __attribute__((ext_vector_type(4)));
typedef __bf16 bf16x8 __attribute__((ext_vector_type(8)));
typedef u16 u16x8 __attribute__((ext_vector_type(8)));
typedef u16 u16x4 __attribute__((ext_vector_type(4)));

__device__ __forceinline__ u16 f2bf(float f) {
    return __builtin_bit_cast(u16, static_cast<__bf16>(f));
}

// ---------------------------------------------------------------------------
// W pack: [Wk|Wq|Wv] f32 -> bf16 in MFMA B-fragment order.
// wp[(n16*32 + kc)*64 + lane] (x8 elems) = W[n16*16 + (lane&15)][kc*32+(lane>>4)*8 ..]
// Wq rows (n16 4..7) pre-scaled by C^-0.5 = 1/32.
// ---------------------------------------------------------------------------
__global__ __launch_bounds__(256) void wpack_kernel(
    const float* __restrict__ Wk, const float* __restrict__ Wq,
    const float* __restrict__ Wv, u16* __restrict__ wp)
{
    int slot = blockIdx.x * 256 + threadIdx.x;   // 0..24575
    int n16  = slot >> 11;
    int rem  = slot & 2047;
    int kc   = rem >> 6;
    int lane = rem & 63;
    int l15 = lane & 15, lg = lane >> 4;
    int col = n16 * 16 + l15;                    // 0..191
    const float* __restrict__ Wm = (col < 64) ? Wk : (col < 128) ? Wq : Wv;
    float sc = (col >= 64 && col < 128) ? 0.03125f : 1.0f;
    const float* src = &Wm[(size_t)(col & 63) * Cn + kc * 32 + lg * 8];
    float4 lo = *reinterpret_cast<const float4*>(src);
    float4 hi = *reinterpret_cast<const float4*>(src + 4);
    u16x8 o;
    o[0] = f2bf(lo.x * sc); o[1] = f2bf(lo.y * sc);
    o[2] = f2bf(lo.z * sc); o[3] = f2bf(lo.w * sc);
    o[4] = f2bf(hi.x * sc); o[5] = f2bf(hi.y * sc);
    o[6] = f2bf(hi.z * sc); o[7] = f2bf(hi.w * sc);
    *reinterpret_cast<u16x8*>(&wp[(size_t)slot * 8]) = o;
}

// ---------------------------------------------------------------------------
// QKV projection, single pass.  grid 256, block 512 (8 waves = 2 rowgroups x
// 4 colgroups of 48).  BM=32, full K=1024 as 16 x BK=64 LDS steps, double-
// buffered with register prefetch (load at loop head, ds_write after compute,
// one barrier/step).  W B-frags stream from packed wp (L2-resident, 1KB/instr
// coalesced).  Direct bf16 k/q/v output — no partials, no merge kernel.
// LDS stride 68 f32 -> 2-way read conflicts (free).
// ---------------------------------------------------------------------------
__global__ __launch_bounds__(512) void qkv_proj(
    const float* __restrict__ x, const u16* __restrict__ wp,
    u16* __restrict__ kb, u16* __restrict__ qb, u16* __restrict__ vb)
{
    __shared__ float xs[2][32 * 68];

    const int tid  = threadIdx.x;
    const int lane = tid & 63;
    const int w    = tid >> 6;        // 0..7
    const int rg   = w & 1;           // rowgroup of 16
    const int cg   = w >> 1;          // colgroup of 48 (3 tiles)
    const int l15  = lane & 15;
    const int lg   = lane >> 4;

    const int row0 = blockIdx.x * 32;
    const int sr   = tid >> 4;          // staging row 0..31
    const int scc  = (tid & 15) << 2;   // staging col 0..60

    f32x4 acc[3];
#pragma unroll
    for (int nt = 0; nt < 3; ++nt)
#pragma unroll
        for (int r = 0; r < 4; ++r) acc[nt][r] = 0.f;

    const float* __restrict__ xsrc = &x[(size_t)(row0 + sr) * Cn + scc];

    // prologue: stage step 0
    float4 g = *reinterpret_cast<const float4*>(xsrc);
    *reinterpret_cast<float4*>(&xs[0][sr * 68 + scc]) = g;
    __syncthreads();

    for (int ks = 0; ks < 16; ++ks) {
        const int cur = ks & 1;
        if (ks < 15)
            g = *reinterpret_cast<const float4*>(xsrc + (ks + 1) * 64);
#pragma unroll
        for (int kc2 = 0; kc2 < 2; ++kc2) {
            const float* ap = &xs[cur][(rg * 16 + l15) * 68 + kc2 * 32 + (lg << 3)];
            f32x4 a0 = *reinterpret_cast<const f32x4*>(ap);
            f32x4 a1 = *reinterpret_cast<const f32x4*>(ap + 4);
            bf16x8 a;
            a[0] = (__bf16)a0[0]; a[1] = (__bf16)a0[1];
            a[2] = (__bf16)a0[2]; a[3] = (__bf16)a0[3];
            a[4] = (__bf16)a1[0]; a[5] = (__bf16)a1[1];
            a[6] = (__bf16)a1[2]; a[7] = (__bf16)a1[3];
            const int kcg = ks * 2 + kc2;
#pragma unroll
            for (int nt = 0; nt < 3; ++nt) {
                const int n16 = cg * 3 + nt;
                bf16x8 bfr = *reinterpret_cast<const bf16x8*>(
                    &wp[(size_t)((n16 * 32 + kcg) * 64 + lane) * 8]);
                acc[nt] = __builtin_amdgcn_mfma_f32_16x16x32_bf16(a, bfr, acc[nt], 0, 0, 0);
            }
        }
        if (ks < 15)
            *reinterpret_cast<float4*>(&xs[cur ^ 1][sr * 68 + scc]) = g;
        __syncthreads();
    }

    // epilogue: D col = l15, row-in-tile = lg*4+reg.  Direct bf16 stores.
#pragma unroll
    for (int nt = 0; nt < 3; ++nt) {
        const int n16  = cg * 3 + nt;
        const int col0 = n16 * 16;
        const int mat  = col0 >> 6;
        u16* __restrict__ ob = (mat == 0) ? kb : (mat == 1) ? qb : vb;
        const int h = (col0 & 63) + l15;
#pragma unroll
        for (int reg = 0; reg < 4; ++reg) {
            const int grow = row0 + rg * 16 + (lg << 2) + reg;
            ob[(size_t)grow * Hn + h] = f2bf(acc[nt][reg]);
        }
    }
}

// ---------------------------------------------------------------------------
// Causal flash attention, split-KV.  Work unit = (b, 32-row qtile, 256-key
// chunk); 1152 uniform blocks.  Block: 4 waves = 2 rowgroups x 2 key-
// parities.  In-block parity merge -> f32 (O,m,l) partial.
// ---------------------------------------------------------------------------
__global__ __launch_bounds__(256) void attn(
    const u16* __restrict__ qb, const u16* __restrict__ kb,
    const u16* __restrict__ vb, float* __restrict__ Opart,
    float* __restrict__ mlb)
{
    __shared__ u16 Ks[2][64 * 72];
    __shared__ u16 VTs[2][64 * 72];
    __shared__ u16 Pl[4][16 * 72];

    const int tid  = threadIdx.x;
    const int lane = tid & 63;
    const int w    = tid >> 6;
    const int g    = w >> 1;
    const int p    = w & 1;
    const int l15  = lane & 15;
    const int lg   = lane >> 4;

    const int bid = blockIdx.x;
    const int b = bid / 288;
    const int r = bid % 288;
    int gq = (int)((sqrtf((float)r + 1.0f) - 1.0f) * 0.5f);
    while (4 * (gq + 1) * (gq + 2) <= r) ++gq;
    while (4 * gq * (gq + 1) > r) --gq;
    const int rr = r - 4 * gq * (gq + 1);
    const int qt = gq * 8 + rr / (gq + 1);
    const int c  = rr % (gq + 1);

    const int t0  = qt * 32;
    const int wr0 = t0 + g * 16;
    const int nkt = ((t0 + 31) >> 6) + 1;
    const size_t kvbase = (size_t)b * Tn * Hn;

    bf16x8 qf[2];
    {
        const u16* qrow = qb + ((size_t)(b * Tn + wr0 + l15)) * Hn;
        qf[0] = *reinterpret_cast<const bf16x8*>(&qrow[(lg << 3)]);
        qf[1] = *reinterpret_cast<const bf16x8*>(&qrow[32 + (lg << 3)]);
    }

    f32x4 o[4];
    float m[4], ls[4];
#pragma unroll
    for (int nt = 0; nt < 4; ++nt)
#pragma unroll
        for (int rg2 = 0; rg2 < 4; ++rg2) o[nt][rg2] = 0.f;
#pragma unroll
    for (int rg2 = 0; rg2 < 4; ++rg2) { m[rg2] = -INFINITY; ls[rg2] = 0.f; }

    for (int s = 0; s < 2; ++s) {
        const int kt0 = c * 4 + 2 * s, kt1 = kt0 + 1;
        if (kt0 < nkt) {
#pragma unroll
            for (int i = 0; i < 2; ++i) {
                int cc = tid + 256 * i;
                int rr2 = cc >> 3, c8 = (cc & 7) << 3;
                *reinterpret_cast<u16x8*>(&Ks[0][rr2 * 72 + c8]) =
                    *reinterpret_cast<const u16x8*>(&kb[kvbase + (size_t)(kt0 * 64 + rr2) * Hn + c8]);
            }
#pragma unroll
            for (int i = 0; i < 2; ++i) {
                int cc = tid + 256 * i;
                int k = cc & 63, d0 = (cc >> 6) << 3;
                u16x8 v = *reinterpret_cast<const u16x8*>(&vb[kvbase + (size_t)(kt0 * 64 + k) * Hn + d0]);
#pragma unroll
                for (int j = 0; j < 8; ++j) VTs[0][(d0 + j) * 72 + k] = v[j];
            }
        }
        if (kt1 < nkt) {
#pragma unroll
            for (int i = 0; i < 2; ++i) {
                int cc = tid + 256 * i;
                int rr2 = cc >> 3, c8 = (cc & 7) << 3;
                *reinterpret_cast<u16x8*>(&Ks[1][rr2 * 72 + c8]) =
                    *reinterpret_cast<const u16x8*>(&kb[kvbase + (size_t)(kt1 * 64 + rr2) * Hn + c8]);
            }
#pragma unroll
            for (int i = 0; i < 2; ++i) {
                int cc = tid + 256 * i;
                int k = cc & 63, d0 = (cc >> 6) << 3;
                u16x8 v = *reinterpret_cast<const u16x8*>(&vb[kvbase + (size_t)(kt1 * 64 + k) * Hn + d0]);
#pragma unroll
                for (int j = 0; j < 8; ++j) VTs[1][(d0 + j) * 72 + k] = v[j];
            }
        }
        __syncthreads();

        const int mykt = kt0 + p;
        if (mykt < nkt) {
            f32x4 sf[4];
#pragma unroll
            for (int nt = 0; nt < 4; ++nt)
#pragma unroll
                for (int rg2 = 0; rg2 < 4; ++rg2) sf[nt][rg2] = 0.f;
#pragma unroll
            for (int kc = 0; kc < 2; ++kc) {
#pragma unroll
                for (int nt = 0; nt < 4; ++nt) {
                    bf16x8 kf = *reinterpret_cast<const bf16x8*>(
                        &Ks[p][(nt * 16 + l15) * 72 + kc * 32 + (lg << 3)]);
                    sf[nt] = __builtin_amdgcn_mfma_f32_16x16x32_bf16(qf[kc], kf, sf[nt], 0, 0, 0);
                }
            }
            if (mykt * 64 + 63 > wr0) {
#pragma unroll
                for (int nt = 0; nt < 4; ++nt) {
                    int kg = mykt * 64 + nt * 16 + l15;
#pragma unroll
                    for (int reg = 0; reg < 4; ++reg) {
                        int tq = wr0 + (lg << 2) + reg;
                        if (kg > tq) sf[nt][reg] = -INFINITY;
                    }
                }
            }
            float pv[4][4];
#pragma unroll
            for (int reg = 0; reg < 4; ++reg) {
                float tm = fmaxf(fmaxf(sf[0][reg], sf[1][reg]),
                                 fmaxf(sf[2][reg], sf[3][reg]));
#pragma unroll
                for (int off = 1; off < 16; off <<= 1)
                    tm = fmaxf(tm, __shfl_xor(tm, off, 64));
                float nm = fmaxf(m[reg], tm);
                float al = __expf(m[reg] - nm);
                float rs = 0.f;
#pragma unroll
                for (int nt = 0; nt < 4; ++nt) {
                    pv[nt][reg] = __expf(sf[nt][reg] - nm);
                    rs += pv[nt][reg];
                }
#pragma unroll
                for (int off = 1; off < 16; off <<= 1)
                    rs += __shfl_xor(rs, off, 64);
                ls[reg] = ls[reg] * al + rs;
                m[reg]  = nm;
#pragma unroll
                for (int nt = 0; nt < 4; ++nt) o[nt][reg] *= al;
            }
#pragma unroll
            for (int nt = 0; nt < 4; ++nt)
#pragma unroll
                for (int reg = 0; reg < 4; ++reg)
                    Pl[w][((lg << 2) + reg) * 72 + nt * 16 + l15] = f2bf(pv[nt][reg]);
#pragma unroll
            for (int kc = 0; kc < 2; ++kc) {
                bf16x8 pa = *reinterpret_cast<const bf16x8*>(
                    &Pl[w][l15 * 72 + kc * 32 + (lg << 3)]);
#pragma unroll
                for (int nt = 0; nt < 4; ++nt) {
                    bf16x8 vf = *reinterpret_cast<const bf16x8*>(
                        &VTs[p][(nt * 16 + l15) * 72 + kc * 32 + (lg << 3)]);
                    o[nt] = __builtin_amdgcn_mfma_f32_16x16x32_bf16(pa, vf, o[nt], 0, 0, 0);
                }
            }
        }
        __syncthreads();
    }

    float* slab = reinterpret_cast<float*>(&Ks[0][0]);
    float* sb = slab + g * (24 * 64);
    if (p == 1) {
#pragma unroll
        for (int nt = 0; nt < 4; ++nt)
#pragma unroll
            for (int reg = 0; reg < 4; ++reg)
                sb[(nt * 4 + reg) * 64 + lane] = o[nt][reg];
#pragma unroll
        for (int reg = 0; reg < 4; ++reg) {
            sb[(16 + reg) * 64 + lane] = m[reg];
            sb[(20 + reg) * 64 + lane] = ls[reg];
        }
    }
    __syncthreads();
    if (p == 0) {
        const size_t pidx = (size_t)(b * 64 + qt) * 8 + c;
        float* __restrict__ ob = Opart + pidx * 2048;
#pragma unroll
        for (int reg = 0; reg < 4; ++reg) {
            float mB = sb[(16 + reg) * 64 + lane];
            float lB = sb[(20 + reg) * 64 + lane];
            float ms = fmaxf(m[reg], mB);
            float aA = __expf(m[reg] - ms);
            float aB = __expf(mB - ms);
            int row32 = g * 16 + (lg << 2) + reg;
            if (l15 == 0) {
                float* mlp = mlb + pidx * 64 + row32 * 2;
                mlp[0] = ms;
                mlp[1] = aA * ls[reg] + aB * lB;
            }
#pragma unroll
            for (int nt = 0; nt < 4; ++nt)
                ob[row32 * 64 + nt * 16 + l15] =
                    aA * o[nt][reg] + aB * sb[(nt * 4 + reg) * 64 + lane];
        }
    }
}

// ---------------------------------------------------------------------------
// Combine KV-chunk partials online.  grid 256, block 256.
// ---------------------------------------------------------------------------
__global__ __launch_bounds__(256) void attn_merge(
    const float* __restrict__ Opart, const float* __restrict__ mlb,
    float* __restrict__ out)
{
    const int bid = blockIdx.x;
    const int b = bid >> 6, qt = bid & 63;
    const int nch = (qt >> 3) + 1;
    const int t = threadIdx.x;
    const int row = t >> 3, d0 = (t & 7) << 3;
    const size_t pbase = (size_t)(b * 64 + qt) * 8;

    float m = -INFINITY, l = 0.f;
    f32x4 O0 = {0.f, 0.f, 0.f, 0.f}, O1 = {0.f, 0.f, 0.f, 0.f};
    for (int cc = 0; cc < nch; ++cc) {
        const float* mlp = mlb + (pbase + cc) * 64 + row * 2;
        float mc = mlp[0], lc = mlp[1];
        float nm = fmaxf(m, mc);
        float a  = __expf(m - nm);
        float ac = __expf(mc - nm);
        const float* op = Opart + (pbase + cc) * 2048 + row * 64 + d0;
        f32x4 c0 = *reinterpret_cast<const f32x4*>(op);
        f32x4 c1 = *reinterpret_cast<const f32x4*>(op + 4);
        O0 = O0 * a + c0 * ac;
        O1 = O1 * a + c1 * ac;
        l  = l * a + lc * ac;
        m  = nm;
    }
    float inv = 1.f / l;
    float* orow = out + ((size_t)(b * Tn + qt * 32 + row)) * Hn + d0;
    *reinterpret_cast<f32x4*>(orow)     = O0 * inv;
    *reinterpret_cast<f32x4*>(orow + 4) = O1 * inv;
}

extern "C" void kernel_launch(void* const* d_in, const int* in_sizes, int n_in,
                              void* d_out, int out_size, void* d_ws, size_t ws_size,
                              hipStream_t stream) {
    const float* x  = (const float*)d_in[0];
    const float* Wk = (const float*)d_in[1];
    const float* Wq = (const float*)d_in[2];
    const float* Wv = (const float*)d_in[3];
    float* out = (float*)d_out;

    const size_t rows = (size_t)4 * Tn;            // 8192
    u16* kbuf = (u16*)d_ws;                        // [8192][64] bf16
    u16* qbuf = kbuf + rows * Hn;
    u16* vbuf = qbuf + rows * Hn;
    u16* wpk  = vbuf + rows * Hn;                  // 196608 u16
    float* Opart = (float*)(wpk + 196608);         // [4][64][8][32][64] f32
    float* mlb   = Opart + (size_t)4 * 64 * 8 * 2048;  // [4][64][8][32][2] f32

    wpack_kernel<<<96, 256, 0, stream>>>(Wk, Wq, Wv, wpk);
    qkv_proj<<<256, 512, 0, stream>>>(x, wpk, kbuf, qbuf, vbuf);
    attn<<<1152, 256, 0, stream>>>(qbuf, kbuf, vbuf, Opart, mlb);
    attn_merge<<<256, 256, 0, stream>>>(Opart, mlb, out);
}